// Round 15
// baseline (109.670 us; speedup 1.0000x reference)
//
#include <hip/hip_runtime.h>
#include <hip/hip_bf16.h>
#include <math.h>

// SkipGRU on MI355X, round 15: FENCELESS chain via MALL-coherent h exchange.
// Unified model from r6-r14: per-sequential-step sync costs ~8-9us whether it
// is an in-kernel __threadfence barrier (r13: 8.6us/step) or a kernel-launch
// boundary (r14: ~9us/step) -> both pay the same cross-XCD L2
// writeback+invalidate. Fix: h passes through the device coherence point
// directly -- stores/loads are RELAXED AGENT-scope atomics (cache-bypassing;
// cross-XCD coherence of these proven by r6-r8 barrier counters), so NO
// threadfence is needed anywhere: __syncthreads' vmcnt(0) drain (compiler-
// guaranteed) means h-stores completed before the leader's fetch_add; the
// consumer's atomic loads fetch fresh data by construction. L2 never gets
// invalidated -> LDS-resident B (r13's proven win) and MX locality survive.
//
// Only chain j=23 contributes to outputs[:, -1, :] (t=191 = chunk 7 lane 23):
// 8 sequential GRU steps over x[:, c*24+23, :], h[256,512].
//
// mfma_f32_16x16x32_bf16 layouts (learn_hip m89-verified, r4-r14 validated):
//   A: lane l holds A[l&15][(l>>4)*8 + j]
//   B: lane l holds B[(l>>4)*8 + j][l&15]  (B^T row-major -> contiguous load)
//   D: lane l reg q -> row (l>>4)*4+q, col l&15
//
// B LDS slice [96 rows][512 k] bf16 staged once via global_load_lds with
// pre-swizzled global source (r13-proven; LDS dest linear per HW rule).

typedef float f32x4 __attribute__((ext_vector_type(4)));
typedef short short8 __attribute__((ext_vector_type(8)));

#define BB 256
#define UU 512
#define KK 512
#define N3 1536
#define NWG 128   // 8 row-groups x 16 col-WGs, 1 WG/CU (96KB LDS) -> co-resident
#define GWG 16    // WGs per row-group (sync domain)

__device__ __forceinline__ float sigmoidf_(float s) {
    return 1.0f / (1.0f + __expf(-s));
}

// Fused prologue: blocks [0,768) transpose ker, [768,1536) transpose rker,
// [1536,2048) gather+convert x, [2048,2052) zero barrier counters.
__global__ __launch_bounds__(256)
void prologue(const float* __restrict__ ker, const float* __restrict__ rker,
              const float* __restrict__ x,
              __hip_bfloat16* __restrict__ Kt, __hip_bfloat16* __restrict__ Rtb,
              __hip_bfloat16* __restrict__ Xb, unsigned* __restrict__ bar)
{
    __shared__ float tile[32][33];
    const int blk = blockIdx.x;
    const int tid = threadIdx.x;
    if (blk < 1536) {
        const float* W = (blk < 768) ? ker : rker;
        __hip_bfloat16* Wt = (blk < 768) ? Kt : Rtb;
        const int b = (blk < 768) ? blk : blk - 768;
        const int xx = tid & 31, yy = tid >> 5;           // (32, 8)
        const int c0 = (b % 48) * 32;                     // C = 1536
        const int r0 = (b / 48) * 32;                     // R = 512
        #pragma unroll
        for (int i = 0; i < 32; i += 8)
            tile[yy + i][xx] = W[(long)(r0 + yy + i) * N3 + c0 + xx];
        __syncthreads();
        #pragma unroll
        for (int i = 0; i < 32; i += 8)
            Wt[(long)(c0 + yy + i) * KK + r0 + xx] = __float2bfloat16(tile[xx][yy + i]);
    } else if (blk < 2048) {
        const int idx = (blk - 1536) * 256 + tid;         // one thread per 8 elems
        const int e = idx * 8;
        const int m = e >> 9;                             // 0..2047 = c*256+b
        const int kk = e & 511;
        const int bb = m & 255, c = m >> 8;
        const float* src = x + (long)bb * (192 * 512) + (long)(c * 24 + 23) * 512 + kk;
        float4 v0 = *(const float4*)src;
        float4 v1 = *(const float4*)(src + 4);
        __hip_bfloat16* dst = Xb + (long)m * 512 + kk;
        dst[0] = __float2bfloat16(v0.x);
        dst[1] = __float2bfloat16(v0.y);
        dst[2] = __float2bfloat16(v0.z);
        dst[3] = __float2bfloat16(v0.w);
        dst[4] = __float2bfloat16(v1.x);
        dst[5] = __float2bfloat16(v1.y);
        dst[6] = __float2bfloat16(v1.z);
        dst[7] = __float2bfloat16(v1.w);
    } else {
        const int i = (blk - 2048) * 256 + tid;
        if (i < 7 * 8 * 16) bar[i] = 0u;
    }
}

// MX = A @ Kt^T + bias:  A[2048][512] bf16, Kt[1536][512] bf16 (=W^T), out f32.
__global__ __launch_bounds__(256)
void gemm_mx(const __hip_bfloat16* __restrict__ A,
             const __hip_bfloat16* __restrict__ Bt,
             const float* __restrict__ bias,
             float* __restrict__ C)
{
    const int tid = threadIdx.x;
    const int lane = tid & 63;
    const int wid = tid >> 6;                    // 0..3
    const int m0 = blockIdx.y * 64 + wid * 16;
    const int n0 = blockIdx.x * 64;
    const int lr = lane & 15;
    const int lk = (lane >> 4) * 8;

    const short8* ap = (const short8*)(A + (long)(m0 + lr) * KK + lk);
    const short8* bp = (const short8*)(Bt + (long)(n0 + lr) * KK + lk);

    f32x4 acc[4] = {{0.f,0.f,0.f,0.f},{0.f,0.f,0.f,0.f},
                    {0.f,0.f,0.f,0.f},{0.f,0.f,0.f,0.f}};
    #pragma unroll
    for (int k = 0; k < 16; ++k) {               // k0 = 32*k
        short8 a = ap[k * 4];
        #pragma unroll
        for (int t = 0; t < 4; ++t) {
            short8 b = bp[t * 1024 + k * 4];     // +16 rows = 16*512/8 short8
            acc[t] = __builtin_amdgcn_mfma_f32_16x16x32_bf16(a, b, acc[t], 0, 0, 0);
        }
    }
    const int row = (lane >> 4) * 4;
    #pragma unroll
    for (int t = 0; t < 4; ++t) {
        const int u = n0 + t * 16 + lr;
        const float bi = bias[u];
        #pragma unroll
        for (int q = 0; q < 4; ++q)
            C[(long)(m0 + row + q) * N3 + u] = acc[t][q] + bi;
    }
}

// Fenceless group barrier (16 WGs). __syncthreads drains each thread's vmem
// queue (compiler emits s_waitcnt vmcnt(0) before s_barrier) -> all coherent
// h-stores COMPLETED at the coherence point before the leader's arrival add.
// No threadfence -> no L2 writeback/invalidate.
__device__ __forceinline__ void group_sync_nf(unsigned* cnt)
{
    __syncthreads();
    if (threadIdx.x == 0) {
        __hip_atomic_fetch_add(cnt, 1u, __ATOMIC_RELAXED,
                               __HIP_MEMORY_SCOPE_AGENT);
        while (__hip_atomic_load(cnt, __ATOMIC_RELAXED,
                                 __HIP_MEMORY_SCOPE_AGENT) < (unsigned)GWG)
            __builtin_amdgcn_s_sleep(4);
    }
    __syncthreads();
}

// Persistent 8-step chain, LDS-resident B, MALL-coherent h exchange.
// 128 WGs x 256 thr (4 waves). WG (by,bx): rows by*32..+32, cols bx*32..+32,
// all 3 gates. Wave w=(wy,wx): 16x16 patch. h own-patch carried in f32 regs.
__global__ __launch_bounds__(256, 1)
void gru_chain(const __hip_bfloat16* __restrict__ Rt,   // [1536][512] bf16
               const float* __restrict__ rbias,         // [1536]
               const float* __restrict__ MX,            // [8][256][1536] f32
               unsigned short* __restrict__ hbA,        // [256][512] bf16 bits
               unsigned short* __restrict__ hbB,
               float* __restrict__ out,                 // [256][512] f32
               unsigned* __restrict__ bar)
{
    __shared__ char Bls[96 * 1024];   // [96 rows][1024 B], source-swizzled
    const int tid = threadIdx.x;
    const int lane = tid & 63;
    const int w = tid >> 6;           // wave 0..3
    const int wy = w >> 1, wx = w & 1;
    const int by = blockIdx.x & 7;    // row-group
    const int bx = blockIdx.x >> 3;   // col WG in group (0..15)
    const int lr = lane & 15;
    const int hi = lane >> 4;         // 0..3
    const int m0 = by * 32 + wy * 16;
    const int n0 = bx * 32;
    const int u  = n0 + wx * 16 + lr;

    // ---- Stage B-slice into LDS (once): 96 rows x 1024B (r13-proven).
    {
        const char* RtB = (const char*)Rt;
        #pragma unroll
        for (int i = 0; i < 24; ++i) {
            const int j  = i * 4 + w;                 // slice row 0..95
            const int gt = j >> 5, cc = j & 31;       // gate, col-in-slice
            const int off = lane * 16;
            const long srcoff = (long)(gt * 512 + n0 + cc) * 1024
                              + (off ^ ((j & 7) << 4));
            __builtin_amdgcn_global_load_lds(
                (const __attribute__((address_space(1))) unsigned int*)(RtB + srcoff),
                (__attribute__((address_space(3))) unsigned int*)(Bls + (long)j * 1024),
                16, 0, 0);
        }
    }

    const float rbz = rbias[u];
    const float rbg = rbias[u + UU];
    const float rbh = rbias[u + 2 * UU];

    float hold[4] = {0.f, 0.f, 0.f, 0.f};

    // MX for step 0 (later steps prefetch before the barrier).
    float mxv[3][4];
    #pragma unroll
    for (int q = 0; q < 4; ++q) {
        const float* p = MX + (long)(m0 + hi * 4 + q) * N3 + u;
        mxv[0][q] = p[0];
        mxv[1][q] = p[UU];
        mxv[2][q] = p[2 * UU];
    }

    #pragma unroll 1
    for (int c = 0; c < 8; ++c) {
        unsigned short* hb_in = (c & 1) ? hbB : hbA;
        unsigned short* hb_o  = (c & 1) ? hbA : hbB;

        f32x4 acc[3] = {{0.f,0.f,0.f,0.f},{0.f,0.f,0.f,0.f},{0.f,0.f,0.f,0.f}};

        if (c > 0) {
            // A-fragments via MALL-coherent 4B loads (64 independent,
            // pipelined; bypass L1/L2 so no fence was needed for visibility).
            unsigned* hp = (unsigned*)hb_in + (long)(m0 + lr) * 256 + hi * 4;
            short8 A[16];
            #pragma unroll
            for (int kk = 0; kk < 16; ++kk) {
                union { unsigned u4[4]; short8 s; } v;
                v.u4[0] = __hip_atomic_load(hp + kk * 16 + 0, __ATOMIC_RELAXED,
                                            __HIP_MEMORY_SCOPE_AGENT);
                v.u4[1] = __hip_atomic_load(hp + kk * 16 + 1, __ATOMIC_RELAXED,
                                            __HIP_MEMORY_SCOPE_AGENT);
                v.u4[2] = __hip_atomic_load(hp + kk * 16 + 2, __ATOMIC_RELAXED,
                                            __HIP_MEMORY_SCOPE_AGENT);
                v.u4[3] = __hip_atomic_load(hp + kk * 16 + 3, __ATOMIC_RELAXED,
                                            __HIP_MEMORY_SCOPE_AGENT);
                A[kk] = v.s;
            }

            #pragma unroll
            for (int kk = 0; kk < 16; ++kk) {
                #pragma unroll
                for (int gt = 0; gt < 3; ++gt) {
                    const short8 b = *(const short8*)(Bls
                        + (long)(gt * 32 + wx * 16 + lr) * 1024
                        + ((kk * 64 + hi * 16) ^ ((lr & 7) << 4)));
                    acc[gt] = __builtin_amdgcn_mfma_f32_16x16x32_bf16(
                        A[kk], b, acc[gt], 0, 0, 0);
                }
            }
        }

        // GRU elementwise update on own patch; coherent 2B h-stores.
        #pragma unroll
        for (int q = 0; q < 4; ++q) {
            const int m = m0 + hi * 4 + q;
            const float z = sigmoidf_(mxv[0][q] + acc[0][q] + rbz);
            const float r = sigmoidf_(mxv[1][q] + acc[1][q] + rbg);
            const float cand = mxv[2][q] + r * (acc[2][q] + rbh);   // reset_after
            const float hh = fmaxf(cand, 0.0f);                     // relu
            const float hn = z * hold[q] + (1.0f - z) * hh;
            hold[q] = hn;
            if (c < 7) {
                union { __hip_bfloat16 b; unsigned short s; } cv;
                cv.b = __float2bfloat16(hn);
                __hip_atomic_store(hb_o + (long)m * UU + u, cv.s,
                                   __ATOMIC_RELAXED, __HIP_MEMORY_SCOPE_AGENT);
            } else {
                out[(long)m * UU + u] = hn;
            }
        }

        if (c < 7) {
            // Prefetch next step's MX before the sync (h-independent, cached).
            #pragma unroll
            for (int q = 0; q < 4; ++q) {
                const float* p = MX + (long)(c + 1) * BB * N3
                               + (long)(m0 + hi * 4 + q) * N3 + u;
                mxv[0][q] = p[0];
                mxv[1][q] = p[UU];
                mxv[2][q] = p[2 * UU];
            }
            group_sync_nf(&bar[(c * 8 + by) * 16]);
        }
    }
}

extern "C" void kernel_launch(void* const* d_in, const int* in_sizes, int n_in,
                              void* d_out, int out_size, void* d_ws, size_t ws_size,
                              hipStream_t stream)
{
    const float* x     = (const float*)d_in[0];   // [256,192,512]
    const float* ker   = (const float*)d_in[1];   // [512,1536]
    const float* rker  = (const float*)d_in[2];   // [512,1536]
    const float* ibias = (const float*)d_in[3];   // [1536]
    const float* rbias = (const float*)d_in[4];   // [1536]
    float* out = (float*)d_out;                   // [256,512]

    char* ws = (char*)d_ws;
    float*          MX   = (float*)ws;                            // 12,582,912 B
    __hip_bfloat16* Xb   = (__hip_bfloat16*)(ws + 12582912);      //  2,097,152 B
    __hip_bfloat16* Kt   = (__hip_bfloat16*)(ws + 14680064);      //  1,572,864 B
    __hip_bfloat16* Rt   = (__hip_bfloat16*)(ws + 16252928);      //  1,572,864 B
    unsigned short* hbA  = (unsigned short*)(ws + 17825792);      //    262,144 B
    unsigned short* hbB  = (unsigned short*)(ws + 18087936);      //    262,144 B
    unsigned*       bar  = (unsigned*)(ws + 18350080);            //      3,584 B

    // Node 1: fused prologue (transposes + x gather/convert + barrier zero)
    prologue<<<2052, 256, 0, stream>>>(ker, rker, x, Kt, Rt, Xb, bar);

    // Node 2: MX = Xsel @ kernel + input_bias
    gemm_mx<<<dim3(N3 / 64, 2048 / 64), 256, 0, stream>>>(Xb, Kt, ibias, MX);

    // Node 3: all 8 GRU steps; B LDS-resident; fenceless coherent h exchange.
    gru_chain<<<NWG, 256, 0, stream>>>(Rt, rbias, MX, hbA, hbB, out, bar);
}

// Round 16
// 92.869 us; speedup vs baseline: 1.1809x; 1.1809x over previous
//
#include <hip/hip_runtime.h>
#include <hip/hip_bf16.h>
#include <math.h>

// SkipGRU on MI355X, round 16: m97-style staged GEMM for MX (single change).
// r15 falsified the fence theory (fenceless chain == fenced chain == 71us);
// per-step sync cost ~8.6us is structural across all mechanisms. Measured by
// subtraction: prologue + gemm_mx = ~38us. gemm_mx was a direct-from-global
// 64^2-tile kernel (~150TF regime); this round replaces it with the m97
// recipe: 128^2 tile, BK=32, 4 waves x (64x64 out, 4x4 frags), A/B staged via
// global_load_lds width=16 (per-lane global src, linear LDS dest), 2-barrier
// K-loop. Chain + prologue FROZEN from r15 for attribution.
//
// Only chain j=23 contributes to outputs[:, -1, :] (t=191 = chunk 7 lane 23):
// 8 sequential GRU steps over x[:, c*24+23, :], h[256,512].
//
// mfma_f32_16x16x32_bf16 layouts (learn_hip m89-verified, r4-r15 validated):
//   A: lane l holds A[l&15][(l>>4)*8 + j]
//   B: lane l holds B[(l>>4)*8 + j][l&15]  (B^T row-major -> contiguous load)
//   D: lane l reg q -> row (l>>4)*4+q, col l&15

typedef float f32x4 __attribute__((ext_vector_type(4)));
typedef short short8 __attribute__((ext_vector_type(8)));

#define BB 256
#define UU 512
#define KK 512
#define N3 1536
#define NWG 128   // chain: 8 row-groups x 16 col-WGs, 1 WG/CU (96KB LDS)
#define GWG 16    // WGs per row-group (sync domain)

__device__ __forceinline__ float sigmoidf_(float s) {
    return 1.0f / (1.0f + __expf(-s));
}

// Fused prologue: blocks [0,768) transpose ker, [768,1536) transpose rker,
// [1536,2048) gather+convert x, [2048,2052) zero barrier counters.
__global__ __launch_bounds__(256)
void prologue(const float* __restrict__ ker, const float* __restrict__ rker,
              const float* __restrict__ x,
              __hip_bfloat16* __restrict__ Kt, __hip_bfloat16* __restrict__ Rtb,
              __hip_bfloat16* __restrict__ Xb, unsigned* __restrict__ bar)
{
    __shared__ float tile[32][33];
    const int blk = blockIdx.x;
    const int tid = threadIdx.x;
    if (blk < 1536) {
        const float* W = (blk < 768) ? ker : rker;
        __hip_bfloat16* Wt = (blk < 768) ? Kt : Rtb;
        const int b = (blk < 768) ? blk : blk - 768;
        const int xx = tid & 31, yy = tid >> 5;           // (32, 8)
        const int c0 = (b % 48) * 32;                     // C = 1536
        const int r0 = (b / 48) * 32;                     // R = 512
        #pragma unroll
        for (int i = 0; i < 32; i += 8)
            tile[yy + i][xx] = W[(long)(r0 + yy + i) * N3 + c0 + xx];
        __syncthreads();
        #pragma unroll
        for (int i = 0; i < 32; i += 8)
            Wt[(long)(c0 + yy + i) * KK + r0 + xx] = __float2bfloat16(tile[xx][yy + i]);
    } else if (blk < 2048) {
        const int idx = (blk - 1536) * 256 + tid;         // one thread per 8 elems
        const int e = idx * 8;
        const int m = e >> 9;                             // 0..2047 = c*256+b
        const int kk = e & 511;
        const int bb = m & 255, c = m >> 8;
        const float* src = x + (long)bb * (192 * 512) + (long)(c * 24 + 23) * 512 + kk;
        float4 v0 = *(const float4*)src;
        float4 v1 = *(const float4*)(src + 4);
        __hip_bfloat16* dst = Xb + (long)m * 512 + kk;
        dst[0] = __float2bfloat16(v0.x);
        dst[1] = __float2bfloat16(v0.y);
        dst[2] = __float2bfloat16(v0.z);
        dst[3] = __float2bfloat16(v0.w);
        dst[4] = __float2bfloat16(v1.x);
        dst[5] = __float2bfloat16(v1.y);
        dst[6] = __float2bfloat16(v1.z);
        dst[7] = __float2bfloat16(v1.w);
    } else {
        const int i = (blk - 2048) * 256 + tid;
        if (i < 7 * 8 * 16) bar[i] = 0u;
    }
}

// MX = A @ Bt^T + bias, m97-style: 128x128 tile, BK=32, LDS-staged via
// global_load_lds width=16. A[2048][512] bf16, Bt[1536][512] bf16, out f32.
// 4 waves: wave w=(wm,wn) computes the 64x64 block (wm*64, wn*64) as 4x4
// fragments. Grid (1536/128, 2048/128) = (12,16). Shapes divide exactly.
__global__ __launch_bounds__(256)
void gemm_mx(const __hip_bfloat16* __restrict__ A,
             const __hip_bfloat16* __restrict__ Bt,
             const float* __restrict__ bias,
             float* __restrict__ C)
{
    __shared__ char Als[8192];   // [128 rows][32 k] bf16, 64B rows, linear
    __shared__ char Bls[8192];   // [128 cols][32 k] bf16
    const int tid = threadIdx.x;
    const int lane = tid & 63;
    const int w = tid >> 6;                 // wave 0..3
    const int wm = w >> 1, wn = w & 1;
    const int m0 = blockIdx.y * 128;
    const int n0 = blockIdx.x * 128;
    const int lr = lane & 15;
    const int hi = lane >> 4;               // 0..3

    // Per-lane staging source decomposition: 64 lanes cover 16 rows x 4
    // 16B-chunks = one 1KB LDS span (16 rows of 64B), matching the HW's
    // dest = wave-uniform base + lane*16.
    const int srow = lane >> 2;             // 0..15
    const int scol = (lane & 3) * 16;       // byte in 64B row

    const char* Ab = (const char*)A;
    const char* Bb = (const char*)Bt;

    f32x4 acc[4][4];
    #pragma unroll
    for (int i = 0; i < 4; ++i)
        #pragma unroll
        for (int j = 0; j < 4; ++j) acc[i][j] = {0.f, 0.f, 0.f, 0.f};

    for (int ks = 0; ks < 16; ++ks) {
        const long k0b = (long)ks * 64;     // 32 k-elems * 2B
        __syncthreads();                    // prior compute done -> overwrite ok
        #pragma unroll
        for (int j = 0; j < 2; ++j) {
            const int r = (w * 2 + j) * 16 + srow;      // tile row/col 0..127
            __builtin_amdgcn_global_load_lds(
                (const __attribute__((address_space(1))) unsigned int*)
                    (Ab + (long)(m0 + r) * 1024 + k0b + scol),
                (__attribute__((address_space(3))) unsigned int*)
                    (Als + (w * 2 + j) * 1024),
                16, 0, 0);
            __builtin_amdgcn_global_load_lds(
                (const __attribute__((address_space(1))) unsigned int*)
                    (Bb + (long)(n0 + r) * 1024 + k0b + scol),
                (__attribute__((address_space(3))) unsigned int*)
                    (Bls + (w * 2 + j) * 1024),
                16, 0, 0);
        }
        __syncthreads();                    // staging complete (vmcnt drained)

        short8 a[4], b[4];
        #pragma unroll
        for (int i = 0; i < 4; ++i)
            a[i] = *(const short8*)(Als + (wm * 64 + i * 16 + lr) * 64 + hi * 16);
        #pragma unroll
        for (int j = 0; j < 4; ++j)
            b[j] = *(const short8*)(Bls + (wn * 64 + j * 16 + lr) * 64 + hi * 16);
        #pragma unroll
        for (int i = 0; i < 4; ++i)
            #pragma unroll
            for (int j = 0; j < 4; ++j)
                acc[i][j] = __builtin_amdgcn_mfma_f32_16x16x32_bf16(
                    a[i], b[j], acc[i][j], 0, 0, 0);
    }

    #pragma unroll
    for (int i = 0; i < 4; ++i)
        #pragma unroll
        for (int j = 0; j < 4; ++j) {
            const int u = n0 + wn * 64 + j * 16 + lr;
            const float bi = bias[u];
            #pragma unroll
            for (int q = 0; q < 4; ++q)
                C[(long)(m0 + wm * 64 + i * 16 + hi * 4 + q) * N3 + u]
                    = acc[i][j][q] + bi;
        }
}

// Fenceless group barrier (16 WGs) -- r15, numerically proven.
__device__ __forceinline__ void group_sync_nf(unsigned* cnt)
{
    __syncthreads();
    if (threadIdx.x == 0) {
        __hip_atomic_fetch_add(cnt, 1u, __ATOMIC_RELAXED,
                               __HIP_MEMORY_SCOPE_AGENT);
        while (__hip_atomic_load(cnt, __ATOMIC_RELAXED,
                                 __HIP_MEMORY_SCOPE_AGENT) < (unsigned)GWG)
            __builtin_amdgcn_s_sleep(4);
    }
    __syncthreads();
}

// Persistent 8-step chain, LDS-resident B, MALL-coherent h exchange (r15).
__global__ __launch_bounds__(256, 1)
void gru_chain(const __hip_bfloat16* __restrict__ Rt,   // [1536][512] bf16
               const float* __restrict__ rbias,         // [1536]
               const float* __restrict__ MX,            // [8][256][1536] f32
               unsigned short* __restrict__ hbA,        // [256][512] bf16 bits
               unsigned short* __restrict__ hbB,
               float* __restrict__ out,                 // [256][512] f32
               unsigned* __restrict__ bar)
{
    __shared__ char Bls[96 * 1024];   // [96 rows][1024 B], source-swizzled
    const int tid = threadIdx.x;
    const int lane = tid & 63;
    const int w = tid >> 6;           // wave 0..3
    const int wy = w >> 1, wx = w & 1;
    const int by = blockIdx.x & 7;    // row-group
    const int bx = blockIdx.x >> 3;   // col WG in group (0..15)
    const int lr = lane & 15;
    const int hi = lane >> 4;         // 0..3
    const int m0 = by * 32 + wy * 16;
    const int n0 = bx * 32;
    const int u  = n0 + wx * 16 + lr;

    // ---- Stage B-slice into LDS (once): 96 rows x 1024B (r13-proven).
    {
        const char* RtB = (const char*)Rt;
        #pragma unroll
        for (int i = 0; i < 24; ++i) {
            const int j  = i * 4 + w;                 // slice row 0..95
            const int gt = j >> 5, cc = j & 31;       // gate, col-in-slice
            const int off = lane * 16;
            const long srcoff = (long)(gt * 512 + n0 + cc) * 1024
                              + (off ^ ((j & 7) << 4));
            __builtin_amdgcn_global_load_lds(
                (const __attribute__((address_space(1))) unsigned int*)(RtB + srcoff),
                (__attribute__((address_space(3))) unsigned int*)(Bls + (long)j * 1024),
                16, 0, 0);
        }
    }

    const float rbz = rbias[u];
    const float rbg = rbias[u + UU];
    const float rbh = rbias[u + 2 * UU];

    float hold[4] = {0.f, 0.f, 0.f, 0.f};

    // MX for step 0 (later steps prefetch before the barrier).
    float mxv[3][4];
    #pragma unroll
    for (int q = 0; q < 4; ++q) {
        const float* p = MX + (long)(m0 + hi * 4 + q) * N3 + u;
        mxv[0][q] = p[0];
        mxv[1][q] = p[UU];
        mxv[2][q] = p[2 * UU];
    }

    #pragma unroll 1
    for (int c = 0; c < 8; ++c) {
        unsigned short* hb_in = (c & 1) ? hbB : hbA;
        unsigned short* hb_o  = (c & 1) ? hbA : hbB;

        f32x4 acc[3] = {{0.f,0.f,0.f,0.f},{0.f,0.f,0.f,0.f},{0.f,0.f,0.f,0.f}};

        if (c > 0) {
            // A-fragments via MALL-coherent 4B loads (proven r15).
            unsigned* hp = (unsigned*)hb_in + (long)(m0 + lr) * 256 + hi * 4;
            short8 A[16];
            #pragma unroll
            for (int kk = 0; kk < 16; ++kk) {
                union { unsigned u4[4]; short8 s; } v;
                v.u4[0] = __hip_atomic_load(hp + kk * 16 + 0, __ATOMIC_RELAXED,
                                            __HIP_MEMORY_SCOPE_AGENT);
                v.u4[1] = __hip_atomic_load(hp + kk * 16 + 1, __ATOMIC_RELAXED,
                                            __HIP_MEMORY_SCOPE_AGENT);
                v.u4[2] = __hip_atomic_load(hp + kk * 16 + 2, __ATOMIC_RELAXED,
                                            __HIP_MEMORY_SCOPE_AGENT);
                v.u4[3] = __hip_atomic_load(hp + kk * 16 + 3, __ATOMIC_RELAXED,
                                            __HIP_MEMORY_SCOPE_AGENT);
                A[kk] = v.s;
            }

            #pragma unroll
            for (int kk = 0; kk < 16; ++kk) {
                #pragma unroll
                for (int gt = 0; gt < 3; ++gt) {
                    const short8 b = *(const short8*)(Bls
                        + (long)(gt * 32 + wx * 16 + lr) * 1024
                        + ((kk * 64 + hi * 16) ^ ((lr & 7) << 4)));
                    acc[gt] = __builtin_amdgcn_mfma_f32_16x16x32_bf16(
                        A[kk], b, acc[gt], 0, 0, 0);
                }
            }
        }

        // GRU elementwise update on own patch; coherent 2B h-stores.
        #pragma unroll
        for (int q = 0; q < 4; ++q) {
            const int m = m0 + hi * 4 + q;
            const float z = sigmoidf_(mxv[0][q] + acc[0][q] + rbz);
            const float r = sigmoidf_(mxv[1][q] + acc[1][q] + rbg);
            const float cand = mxv[2][q] + r * (acc[2][q] + rbh);   // reset_after
            const float hh = fmaxf(cand, 0.0f);                     // relu
            const float hn = z * hold[q] + (1.0f - z) * hh;
            hold[q] = hn;
            if (c < 7) {
                union { __hip_bfloat16 b; unsigned short s; } cv;
                cv.b = __float2bfloat16(hn);
                __hip_atomic_store(hb_o + (long)m * UU + u, cv.s,
                                   __ATOMIC_RELAXED, __HIP_MEMORY_SCOPE_AGENT);
            } else {
                out[(long)m * UU + u] = hn;
            }
        }

        if (c < 7) {
            // Prefetch next step's MX before the sync (h-independent, cached).
            #pragma unroll
            for (int q = 0; q < 4; ++q) {
                const float* p = MX + (long)(c + 1) * BB * N3
                               + (long)(m0 + hi * 4 + q) * N3 + u;
                mxv[0][q] = p[0];
                mxv[1][q] = p[UU];
                mxv[2][q] = p[2 * UU];
            }
            group_sync_nf(&bar[(c * 8 + by) * 16]);
        }
    }
}

extern "C" void kernel_launch(void* const* d_in, const int* in_sizes, int n_in,
                              void* d_out, int out_size, void* d_ws, size_t ws_size,
                              hipStream_t stream)
{
    const float* x     = (const float*)d_in[0];   // [256,192,512]
    const float* ker   = (const float*)d_in[1];   // [512,1536]
    const float* rker  = (const float*)d_in[2];   // [512,1536]
    const float* ibias = (const float*)d_in[3];   // [1536]
    const float* rbias = (const float*)d_in[4];   // [1536]
    float* out = (float*)d_out;                   // [256,512]

    char* ws = (char*)d_ws;
    float*          MX   = (float*)ws;                            // 12,582,912 B
    __hip_bfloat16* Xb   = (__hip_bfloat16*)(ws + 12582912);      //  2,097,152 B
    __hip_bfloat16* Kt   = (__hip_bfloat16*)(ws + 14680064);      //  1,572,864 B
    __hip_bfloat16* Rt   = (__hip_bfloat16*)(ws + 16252928);      //  1,572,864 B
    unsigned short* hbA  = (unsigned short*)(ws + 17825792);      //    262,144 B
    unsigned short* hbB  = (unsigned short*)(ws + 18087936);      //    262,144 B
    unsigned*       bar  = (unsigned*)(ws + 18350080);            //      3,584 B

    // Node 1: fused prologue (transposes + x gather/convert + barrier zero)
    prologue<<<2052, 256, 0, stream>>>(ker, rker, x, Kt, Rt, Xb, bar);

    // Node 2: MX = Xsel @ kernel + input_bias (m97-style staged, 128^2 tile)
    gemm_mx<<<dim3(N3 / 128, 2048 / 128), 256, 0, stream>>>(Xb, Kt, ibias, MX);

    // Node 3: all 8 GRU steps; B LDS-resident; fenceless coherent h exchange.
    gru_chain<<<NWG, 256, 0, stream>>>(Rt, rbias, MX, hbA, hbB, out, bar);
}

// Round 17
// 81.933 us; speedup vs baseline: 1.3385x; 1.1335x over previous
//
#include <hip/hip_runtime.h>
#include <hip/hip_bf16.h>
#include <math.h>

// SkipGRU on MI355X, round 17: DMA-only chain body.
// Unified model (r12/r13/r14/r15): per-thread global fragment loads serialize
// at ~400cyc each under VGPR starvation (VGPR=132, no TLP at 4 waves/CU) ->
// ~6-8us/step exposed latency. The sync mechanism was never the cost (fenced
// == fenceless == kernel-boundary). Fix: ZERO per-thread global loads in the
// step loop -- A (h rows) and MX patches are staged by global_load_lds DMA
// (fire-and-forget, no VGPRs), h global layout pre-swizzled by its writers,
// MX double-buffered so chunk c+1 stages during step c.
//
// Only chain j=23 contributes to outputs[:, -1, :] (t=191 = chunk 7 lane 23):
// 8 sequential GRU steps over x[:, c*24+23, :], h[256,512].
//
// mfma_f32_16x16x32_bf16 layouts (learn_hip m89-verified, r4-r16 validated):
//   A: lane l holds A[l&15][(l>>4)*8 + j]
//   B: lane l holds B[(l>>4)*8 + j][l&15]  (B^T row-major -> contiguous load)
//   D: lane l reg q -> row (l>>4)*4+q, col l&15
//
// Swizzle rule (both h and B): global row of 1024B stores byte o at o ^
// ((row&7)<<4); global_load_lds copies rows linearly; ds_read applies the
// same XOR (involution) -> conflict-free LDS reads, per guide §6 G4 + m173.

typedef float f32x4 __attribute__((ext_vector_type(4)));
typedef short short8 __attribute__((ext_vector_type(8)));

#define BB 256
#define UU 512
#define KK 512
#define N3 1536
#define NWG 128   // chain: 8 row-groups x 16 col-WGs, 1 WG/CU (152KB LDS)
#define GWG 16    // WGs per row-group (sync domain)

__device__ __forceinline__ float sigmoidf_(float s) {
    return 1.0f / (1.0f + __expf(-s));
}

// Fused prologue: blocks [0,768) transpose ker, [768,1536) transpose rker,
// [1536,2048) gather+convert x, [2048,2052) zero barrier counters.
__global__ __launch_bounds__(256)
void prologue(const float* __restrict__ ker, const float* __restrict__ rker,
              const float* __restrict__ x,
              __hip_bfloat16* __restrict__ Kt, __hip_bfloat16* __restrict__ Rtb,
              __hip_bfloat16* __restrict__ Xb, unsigned* __restrict__ bar)
{
    __shared__ float tile[32][33];
    const int blk = blockIdx.x;
    const int tid = threadIdx.x;
    if (blk < 1536) {
        const float* W = (blk < 768) ? ker : rker;
        __hip_bfloat16* Wt = (blk < 768) ? Kt : Rtb;
        const int b = (blk < 768) ? blk : blk - 768;
        const int xx = tid & 31, yy = tid >> 5;           // (32, 8)
        const int c0 = (b % 48) * 32;                     // C = 1536
        const int r0 = (b / 48) * 32;                     // R = 512
        #pragma unroll
        for (int i = 0; i < 32; i += 8)
            tile[yy + i][xx] = W[(long)(r0 + yy + i) * N3 + c0 + xx];
        __syncthreads();
        #pragma unroll
        for (int i = 0; i < 32; i += 8)
            Wt[(long)(c0 + yy + i) * KK + r0 + xx] = __float2bfloat16(tile[xx][yy + i]);
    } else if (blk < 2048) {
        const int idx = (blk - 1536) * 256 + tid;         // one thread per 8 elems
        const int e = idx * 8;
        const int m = e >> 9;                             // 0..2047 = c*256+b
        const int kk = e & 511;
        const int bb = m & 255, c = m >> 8;
        const float* src = x + (long)bb * (192 * 512) + (long)(c * 24 + 23) * 512 + kk;
        float4 v0 = *(const float4*)src;
        float4 v1 = *(const float4*)(src + 4);
        __hip_bfloat16* dst = Xb + (long)m * 512 + kk;
        dst[0] = __float2bfloat16(v0.x);
        dst[1] = __float2bfloat16(v0.y);
        dst[2] = __float2bfloat16(v0.z);
        dst[3] = __float2bfloat16(v0.w);
        dst[4] = __float2bfloat16(v1.x);
        dst[5] = __float2bfloat16(v1.y);
        dst[6] = __float2bfloat16(v1.z);
        dst[7] = __float2bfloat16(v1.w);
    } else {
        const int i = (blk - 2048) * 256 + tid;
        if (i < 7 * 8 * 16) bar[i] = 0u;
    }
}

// MX = A @ Bt^T + bias, m97-style (r16-proven): 128x128 tile, BK=32, staged
// via global_load_lds width=16. Grid (12,16).
__global__ __launch_bounds__(256)
void gemm_mx(const __hip_bfloat16* __restrict__ A,
             const __hip_bfloat16* __restrict__ Bt,
             const float* __restrict__ bias,
             float* __restrict__ C)
{
    __shared__ char Als[8192];
    __shared__ char Bls[8192];
    const int tid = threadIdx.x;
    const int lane = tid & 63;
    const int w = tid >> 6;
    const int wm = w >> 1, wn = w & 1;
    const int m0 = blockIdx.y * 128;
    const int n0 = blockIdx.x * 128;
    const int lr = lane & 15;
    const int hi = lane >> 4;

    const int srow = lane >> 2;
    const int scol = (lane & 3) * 16;

    const char* Ab = (const char*)A;
    const char* Bb = (const char*)Bt;

    f32x4 acc[4][4];
    #pragma unroll
    for (int i = 0; i < 4; ++i)
        #pragma unroll
        for (int j = 0; j < 4; ++j) acc[i][j] = {0.f, 0.f, 0.f, 0.f};

    for (int ks = 0; ks < 16; ++ks) {
        const long k0b = (long)ks * 64;
        __syncthreads();
        #pragma unroll
        for (int j = 0; j < 2; ++j) {
            const int r = (w * 2 + j) * 16 + srow;
            __builtin_amdgcn_global_load_lds(
                (const __attribute__((address_space(1))) unsigned int*)
                    (Ab + (long)(m0 + r) * 1024 + k0b + scol),
                (__attribute__((address_space(3))) unsigned int*)
                    (Als + (w * 2 + j) * 1024),
                16, 0, 0);
            __builtin_amdgcn_global_load_lds(
                (const __attribute__((address_space(1))) unsigned int*)
                    (Bb + (long)(n0 + r) * 1024 + k0b + scol),
                (__attribute__((address_space(3))) unsigned int*)
                    (Bls + (w * 2 + j) * 1024),
                16, 0, 0);
        }
        __syncthreads();

        short8 a[4], b[4];
        #pragma unroll
        for (int i = 0; i < 4; ++i)
            a[i] = *(const short8*)(Als + (wm * 64 + i * 16 + lr) * 64 + hi * 16);
        #pragma unroll
        for (int j = 0; j < 4; ++j)
            b[j] = *(const short8*)(Bls + (wn * 64 + j * 16 + lr) * 64 + hi * 16);
        #pragma unroll
        for (int i = 0; i < 4; ++i)
            #pragma unroll
            for (int j = 0; j < 4; ++j)
                acc[i][j] = __builtin_amdgcn_mfma_f32_16x16x32_bf16(
                    a[i], b[j], acc[i][j], 0, 0, 0);
    }

    #pragma unroll
    for (int i = 0; i < 4; ++i)
        #pragma unroll
        for (int j = 0; j < 4; ++j) {
            const int u = n0 + wn * 64 + j * 16 + lr;
            const float bi = bias[u];
            #pragma unroll
            for (int q = 0; q < 4; ++q)
                C[(long)(m0 + wm * 64 + i * 16 + hi * 4 + q) * N3 + u]
                    = acc[i][j][q] + bi;
        }
}

// Persistent 8-step chain: DMA-only body. 128 WGs x 256 thr (4 waves).
// WG (by,bx): rows by*32..+32, cols bx*32..+32, all 3 gates.
__global__ __launch_bounds__(256, 1)
void gru_chain(const __hip_bfloat16* __restrict__ Rt,   // [1536][512] bf16
               const float* __restrict__ rbias,         // [1536]
               const float* __restrict__ MX,            // [8][256][1536] f32
               char* __restrict__ hbA,                  // [256 rows][1024B] swz
               char* __restrict__ hbB,
               float* __restrict__ out,                 // [256][512] f32
               unsigned* __restrict__ bar)
{
    __shared__ char Bls[96 * 1024];     // B slice, source-swizzled (r13)
    __shared__ char Als[32 * 1024];     // h rows (32 x 1KB), source-swizzled
    __shared__ char MXls[2][12288];     // [gate][row][col] f32, double-buffered
    const int tid = threadIdx.x;
    const int lane = tid & 63;
    const int w = tid >> 6;             // wave 0..3
    const int wy = w >> 1, wx = w & 1;
    const int by = blockIdx.x & 7;      // row-group
    const int bx = blockIdx.x >> 3;     // col WG in group (0..15)
    const int lr = lane & 15;
    const int hi = lane >> 4;           // 0..3
    const int m0 = by * 32 + wy * 16;
    const int n0 = bx * 32;
    const int u  = n0 + wx * 16 + lr;

    // ---- Stage B-slice into LDS (once): 96 rows x 1024B (r13-proven).
    {
        const char* RtB = (const char*)Rt;
        #pragma unroll
        for (int i = 0; i < 24; ++i) {
            const int j  = i * 4 + w;
            const int gt = j >> 5, cc = j & 31;
            const long srcoff = (long)(gt * 512 + n0 + cc) * 1024
                              + ((lane * 16) ^ ((j & 7) << 4));
            __builtin_amdgcn_global_load_lds(
                (const __attribute__((address_space(1))) unsigned int*)(RtB + srcoff),
                (__attribute__((address_space(3))) unsigned int*)(Bls + (long)j * 1024),
                16, 0, 0);
        }
    }
    // ---- Stage MX chunk 0 -> MXls[0] (gather-DMA; per-lane source allowed).
    {
        const char* MXb = (const char*)MX;
        #pragma unroll
        for (int jj = 0; jj < 3; ++jj) {
            const int k = w + 4 * jj;              // 0..11, wave-uniform
            const int gt = k >> 2, rblk = k & 3;
            const long src = (long)(by * 32 + rblk * 8 + (lane >> 3)) * 6144
                           + gt * 2048 + bx * 128 + (lane & 7) * 16;
            __builtin_amdgcn_global_load_lds(
                (const __attribute__((address_space(1))) unsigned int*)(MXb + src),
                (__attribute__((address_space(3))) unsigned int*)
                    (MXls[0] + gt * 4096 + rblk * 1024),
                16, 0, 0);
        }
    }

    const float rbz = rbias[u];
    const float rbg = rbias[u + UU];
    const float rbh = rbias[u + 2 * UU];
    float hold[4] = {0.f, 0.f, 0.f, 0.f};

    #pragma unroll 1
    for (int c = 0; c < 8; ++c) {
        char* hb_in = (c & 1) ? hbB : hbA;
        char* hb_o  = (c & 1) ? hbA : hbB;

        // Issue this step's A-DMA (h_{c-1}, visible per prior fenced barrier).
        if (c > 0) {
            #pragma unroll
            for (int i = 0; i < 8; ++i) {
                const int j = i * 4 + w;           // 0..31, wave-uniform
                __builtin_amdgcn_global_load_lds(
                    (const __attribute__((address_space(1))) unsigned int*)
                        (hb_in + (long)(by * 32 + j) * 1024 + lane * 16),
                    (__attribute__((address_space(3))) unsigned int*)
                        (Als + (long)j * 1024),
                    16, 0, 0);
            }
        }
        // Issue next chunk's MX-DMA into the other buffer (h-independent).
        if (c < 7) {
            const char* MXb = (const char*)(MX + (long)(c + 1) * BB * N3);
            #pragma unroll
            for (int jj = 0; jj < 3; ++jj) {
                const int k = w + 4 * jj;
                const int gt = k >> 2, rblk = k & 3;
                const long src = (long)(by * 32 + rblk * 8 + (lane >> 3)) * 6144
                               + gt * 2048 + bx * 128 + (lane & 7) * 16;
                __builtin_amdgcn_global_load_lds(
                    (const __attribute__((address_space(1))) unsigned int*)(MXb + src),
                    (__attribute__((address_space(3))) unsigned int*)
                        (MXls[(c + 1) & 1] + gt * 4096 + rblk * 1024),
                    16, 0, 0);
            }
        }
        __syncthreads();   // drains all DMAs (vmcnt(0) before s_barrier)

        f32x4 acc[3] = {{0.f,0.f,0.f,0.f},{0.f,0.f,0.f,0.f},{0.f,0.f,0.f,0.f}};
        if (c > 0) {
            #pragma unroll
            for (int kk = 0; kk < 16; ++kk) {
                const short8 a = *(const short8*)(Als + (wy * 16 + lr) * 1024
                    + ((kk * 64 + hi * 16) ^ ((lr & 7) << 4)));
                #pragma unroll
                for (int gt = 0; gt < 3; ++gt) {
                    const short8 b = *(const short8*)(Bls
                        + (long)(gt * 32 + wx * 16 + lr) * 1024
                        + ((kk * 64 + hi * 16) ^ ((lr & 7) << 4)));
                    acc[gt] = __builtin_amdgcn_mfma_f32_16x16x32_bf16(
                        a, b, acc[gt], 0, 0, 0);
                }
            }
        }

        // Epilogue: MX from LDS, GRU update, h store (pre-swizzled global).
        const char* mxb = MXls[c & 1];
        #pragma unroll
        for (int q = 0; q < 4; ++q) {
            const int rloc = wy * 16 + hi * 4 + q;         // 0..31
            const float xz = *(const float*)(mxb + 0 * 4096 + rloc * 128 + (wx * 16 + lr) * 4);
            const float xr = *(const float*)(mxb + 1 * 4096 + rloc * 128 + (wx * 16 + lr) * 4);
            const float xh = *(const float*)(mxb + 2 * 4096 + rloc * 128 + (wx * 16 + lr) * 4);
            const float z = sigmoidf_(xz + acc[0][q] + rbz);
            const float r = sigmoidf_(xr + acc[1][q] + rbg);
            const float cand = xh + r * (acc[2][q] + rbh);   // reset_after
            const float hh = fmaxf(cand, 0.0f);              // relu
            const float hn = z * hold[q] + (1.0f - z) * hh;
            hold[q] = hn;
            const int m = m0 + hi * 4 + q;
            if (c < 7) {
                union { __hip_bfloat16 b; unsigned short s; } cv;
                cv.b = __float2bfloat16(hn);
                *(unsigned short*)(hb_o + (long)m * 1024
                    + ((u * 2) ^ ((m & 7) << 4))) = cv.s;
            } else {
                out[(long)m * UU + u] = hn;
            }
        }

        if (c < 7) {
            // Fenced group barrier (r13-proven: release + arrival, relaxed
            // load spin + s_sleep, acquire on exit).
            __syncthreads();
            if (tid == 0) {
                __threadfence();
                __hip_atomic_fetch_add(&bar[(c * 8 + by) * 16], 1u,
                                       __ATOMIC_RELAXED, __HIP_MEMORY_SCOPE_AGENT);
                while (__hip_atomic_load(&bar[(c * 8 + by) * 16],
                                         __ATOMIC_RELAXED,
                                         __HIP_MEMORY_SCOPE_AGENT) < (unsigned)GWG)
                    __builtin_amdgcn_s_sleep(4);
                __threadfence();
            }
            __syncthreads();
        }
    }
}

extern "C" void kernel_launch(void* const* d_in, const int* in_sizes, int n_in,
                              void* d_out, int out_size, void* d_ws, size_t ws_size,
                              hipStream_t stream)
{
    const float* x     = (const float*)d_in[0];   // [256,192,512]
    const float* ker   = (const float*)d_in[1];   // [512,1536]
    const float* rker  = (const float*)d_in[2];   // [512,1536]
    const float* ibias = (const float*)d_in[3];   // [1536]
    const float* rbias = (const float*)d_in[4];   // [1536]
    float* out = (float*)d_out;                   // [256,512]

    char* ws = (char*)d_ws;
    float*          MX   = (float*)ws;                            // 12,582,912 B
    __hip_bfloat16* Xb   = (__hip_bfloat16*)(ws + 12582912);      //  2,097,152 B
    __hip_bfloat16* Kt   = (__hip_bfloat16*)(ws + 14680064);      //  1,572,864 B
    __hip_bfloat16* Rt   = (__hip_bfloat16*)(ws + 16252928);      //  1,572,864 B
    char*           hbA  = (char*)(ws + 17825792);                //    262,144 B
    char*           hbB  = (char*)(ws + 18087936);                //    262,144 B
    unsigned*       bar  = (unsigned*)(ws + 18350080);            //      3,584 B

    // Node 1: fused prologue (transposes + x gather/convert + barrier zero)
    prologue<<<2052, 256, 0, stream>>>(ker, rker, x, Kt, Rt, Xb, bar);

    // Node 2: MX = Xsel @ kernel + input_bias (m97-style staged, 128^2 tile)
    gemm_mx<<<dim3(N3 / 128, 2048 / 128), 256, 0, stream>>>(Xb, Kt, ibias, MX);

    // Node 3: all 8 GRU steps; DMA-only body; fenced group sync.
    gru_chain<<<NWG, 256, 0, stream>>>(Rt, rbias, MX, hbA, hbB, out, bar);
}

// Round 20
// 59.467 us; speedup vs baseline: 1.8442x; 1.3778x over previous
//
#include <hip/hip_runtime.h>
#include <hip/hip_bf16.h>
#include <math.h>

// SkipGRU on MI355X, round 18 design (3rd submit; broker container dead in
// r18/r19): kernel-per-step + DMA-staged body.
// r17 decomposition: chain body ~0.5us/step; the ~7.5us/step residual is the
// h-exchange+barrier round trip (invariant across 6 sync mechanisms). The
// kernel boundary does that same visibility for ~0.5us (r10/r13 subtraction:
// node overhead ~0.5us; r14's 9us steps were per-thread-load BODY cost).
// This round: 7 step KERNELS, each staging B(96KB)+A(32KB)+MX(12KB) via
// global_load_lds (r17-proven addressing), one __syncthreads drain, 48 MFMA,
// epilogue. No barriers, no fences, no persistent state. hf (f32 carry)
// lives in Xb's workspace (dead after gemm_mx).
//
// Only chain j=23 contributes to outputs[:, -1, :] (t=191 = chunk 7 lane 23):
// 8 sequential GRU steps over x[:, c*24+23, :], h[256,512].
//
// mfma_f32_16x16x32_bf16 layouts (learn_hip m89-verified, r4-r17 validated):
//   A: lane l holds A[l&15][(l>>4)*8 + j]
//   B: lane l holds B[(l>>4)*8 + j][l&15]  (B^T row-major -> contiguous load)
//   D: lane l reg q -> row (l>>4)*4+q, col l&15
//
// Swizzle rule (h and B): global row of 1024B stores byte o at o^((row&7)<<4);
// global_load_lds copies rows linearly; ds_read applies the same XOR
// (involution) -> conflict-free LDS reads (guide §6 G4 + m173; r13/r17-proven).

typedef float f32x4 __attribute__((ext_vector_type(4)));
typedef short short8 __attribute__((ext_vector_type(8)));

#define BB 256
#define UU 512
#define KK 512
#define N3 1536

__device__ __forceinline__ float sigmoidf_(float s) {
    return 1.0f / (1.0f + __expf(-s));
}

// Fused prologue: blocks [0,768) transpose ker, [768,1536) transpose rker,
// [1536,2048) gather+convert x.
__global__ __launch_bounds__(256)
void prologue(const float* __restrict__ ker, const float* __restrict__ rker,
              const float* __restrict__ x,
              __hip_bfloat16* __restrict__ Kt, __hip_bfloat16* __restrict__ Rtb,
              __hip_bfloat16* __restrict__ Xb)
{
    __shared__ float tile[32][33];
    const int blk = blockIdx.x;
    const int tid = threadIdx.x;
    if (blk < 1536) {
        const float* W = (blk < 768) ? ker : rker;
        __hip_bfloat16* Wt = (blk < 768) ? Kt : Rtb;
        const int b = (blk < 768) ? blk : blk - 768;
        const int xx = tid & 31, yy = tid >> 5;           // (32, 8)
        const int c0 = (b % 48) * 32;                     // C = 1536
        const int r0 = (b / 48) * 32;                     // R = 512
        #pragma unroll
        for (int i = 0; i < 32; i += 8)
            tile[yy + i][xx] = W[(long)(r0 + yy + i) * N3 + c0 + xx];
        __syncthreads();
        #pragma unroll
        for (int i = 0; i < 32; i += 8)
            Wt[(long)(c0 + yy + i) * KK + r0 + xx] = __float2bfloat16(tile[xx][yy + i]);
    } else {
        const int idx = (blk - 1536) * 256 + tid;         // one thread per 8 elems
        const int e = idx * 8;
        const int m = e >> 9;                             // 0..2047 = c*256+b
        const int kk = e & 511;
        const int bb = m & 255, c = m >> 8;
        const float* src = x + (long)bb * (192 * 512) + (long)(c * 24 + 23) * 512 + kk;
        float4 v0 = *(const float4*)src;
        float4 v1 = *(const float4*)(src + 4);
        __hip_bfloat16* dst = Xb + (long)m * 512 + kk;
        dst[0] = __float2bfloat16(v0.x);
        dst[1] = __float2bfloat16(v0.y);
        dst[2] = __float2bfloat16(v0.z);
        dst[3] = __float2bfloat16(v0.w);
        dst[4] = __float2bfloat16(v1.x);
        dst[5] = __float2bfloat16(v1.y);
        dst[6] = __float2bfloat16(v1.z);
        dst[7] = __float2bfloat16(v1.w);
    }
}

// MX = A @ Bt^T + bias, m97-style (r16-proven): 128x128 tile, BK=32, staged
// via global_load_lds width=16. Grid (12,16).
__global__ __launch_bounds__(256)
void gemm_mx(const __hip_bfloat16* __restrict__ A,
             const __hip_bfloat16* __restrict__ Bt,
             const float* __restrict__ bias,
             float* __restrict__ C)
{
    __shared__ char Als[8192];
    __shared__ char Bls[8192];
    const int tid = threadIdx.x;
    const int lane = tid & 63;
    const int w = tid >> 6;
    const int wm = w >> 1, wn = w & 1;
    const int m0 = blockIdx.y * 128;
    const int n0 = blockIdx.x * 128;
    const int lr = lane & 15;
    const int hi = lane >> 4;

    const int srow = lane >> 2;
    const int scol = (lane & 3) * 16;

    const char* Ab = (const char*)A;
    const char* Bb = (const char*)Bt;

    f32x4 acc[4][4];
    #pragma unroll
    for (int i = 0; i < 4; ++i)
        #pragma unroll
        for (int j = 0; j < 4; ++j) acc[i][j] = {0.f, 0.f, 0.f, 0.f};

    for (int ks = 0; ks < 16; ++ks) {
        const long k0b = (long)ks * 64;
        __syncthreads();
        #pragma unroll
        for (int j = 0; j < 2; ++j) {
            const int r = (w * 2 + j) * 16 + srow;
            __builtin_amdgcn_global_load_lds(
                (const __attribute__((address_space(1))) unsigned int*)
                    (Ab + (long)(m0 + r) * 1024 + k0b + scol),
                (__attribute__((address_space(3))) unsigned int*)
                    (Als + (w * 2 + j) * 1024),
                16, 0, 0);
            __builtin_amdgcn_global_load_lds(
                (const __attribute__((address_space(1))) unsigned int*)
                    (Bb + (long)(n0 + r) * 1024 + k0b + scol),
                (__attribute__((address_space(3))) unsigned int*)
                    (Bls + (w * 2 + j) * 1024),
                16, 0, 0);
        }
        __syncthreads();

        short8 a[4], b[4];
        #pragma unroll
        for (int i = 0; i < 4; ++i)
            a[i] = *(const short8*)(Als + (wm * 64 + i * 16 + lr) * 64 + hi * 16);
        #pragma unroll
        for (int j = 0; j < 4; ++j)
            b[j] = *(const short8*)(Bls + (wn * 64 + j * 16 + lr) * 64 + hi * 16);
        #pragma unroll
        for (int i = 0; i < 4; ++i)
            #pragma unroll
            for (int j = 0; j < 4; ++j)
                acc[i][j] = __builtin_amdgcn_mfma_f32_16x16x32_bf16(
                    a[i], b[j], acc[i][j], 0, 0, 0);
    }

    #pragma unroll
    for (int i = 0; i < 4; ++i)
        #pragma unroll
        for (int j = 0; j < 4; ++j) {
            const int u = n0 + wn * 64 + j * 16 + lr;
            const float bi = bias[u];
            #pragma unroll
            for (int q = 0; q < 4; ++q)
                C[(long)(m0 + wm * 64 + i * 16 + hi * 4 + q) * N3 + u]
                    = acc[i][j][q] + bi;
        }
}

// Step 0 (h==0): mi = rbias, pure elementwise. Writes f32 hf + swizzled bf16.
__global__ __launch_bounds__(256)
void gru_step0(const float* __restrict__ MX0,         // [256][1536] f32
               const float* __restrict__ rbias,       // [1536]
               float* __restrict__ hf_out,            // [256][512] f32
               char* __restrict__ hb_out)             // [256 rows][1024B] swz
{
    const int idx = blockIdx.x * 256 + threadIdx.x;   // b*512 + u
    const int b = idx >> 9;
    const int u = idx & 511;
    const float* mx = MX0 + (long)b * N3;
    const float z = sigmoidf_(mx[u]          + rbias[u]);
    const float r = sigmoidf_(mx[u + UU]     + rbias[u + UU]);
    const float cand = mx[u + 2 * UU] + r * rbias[u + 2 * UU];
    const float hh = fmaxf(cand, 0.0f);
    const float hn = (1.0f - z) * hh;
    hf_out[idx] = hn;
    union { __hip_bfloat16 bf; unsigned short s; } cv;
    cv.bf = __float2bfloat16(hn);
    *(unsigned short*)(hb_out + (long)b * 1024 + ((u * 2) ^ ((b & 7) << 4))) = cv.s;
}

// One GRU step, DMA-staged body (r17-proven addressing). 128 WGs x 256 thr.
// WG (by=blockIdx&7, bx=blockIdx>>3): rows by*32..+32, cols bx*32..+32.
__global__ __launch_bounds__(256)
void gru_step(const __hip_bfloat16* __restrict__ Rt,   // [1536][512] bf16
              const float* __restrict__ rbias,         // [1536]
              const float* __restrict__ MXc,           // [256][1536] f32 chunk c
              const char* __restrict__ hb_in,          // [256 rows][1024B] swz
              const float* __restrict__ hf_in,         // [256][512] f32
              char* __restrict__ hb_out,
              float* __restrict__ hf_out,
              float* __restrict__ out,                 // [256][512] f32
              int last)
{
    __shared__ char Bls[96 * 1024];     // B slice, source-swizzled
    __shared__ char Als[32 * 1024];     // h rows (32 x 1KB), source-swizzled
    __shared__ char MXls[12288];        // [gate][32 rows][32 cols] f32
    const int tid = threadIdx.x;
    const int lane = tid & 63;
    const int w = tid >> 6;             // wave 0..3
    const int wy = w >> 1, wx = w & 1;
    const int by = blockIdx.x & 7;
    const int bx = blockIdx.x >> 3;
    const int lr = lane & 15;
    const int hi = lane >> 4;           // 0..3
    const int m0 = by * 32 + wy * 16;
    const int n0 = bx * 32;
    const int u  = n0 + wx * 16 + lr;

    // ---- Stage B-slice (96 rows x 1024B, r13-proven).
    {
        const char* RtB = (const char*)Rt;
        #pragma unroll
        for (int i = 0; i < 24; ++i) {
            const int j  = i * 4 + w;
            const int gt = j >> 5, cc = j & 31;
            const long srcoff = (long)(gt * 512 + n0 + cc) * 1024
                              + ((lane * 16) ^ ((j & 7) << 4));
            __builtin_amdgcn_global_load_lds(
                (const __attribute__((address_space(1))) unsigned int*)(RtB + srcoff),
                (__attribute__((address_space(3))) unsigned int*)(Bls + (long)j * 1024),
                16, 0, 0);
        }
    }
    // ---- Stage A (h rows, 32 x 1KB).
    #pragma unroll
    for (int i = 0; i < 8; ++i) {
        const int j = i * 4 + w;
        __builtin_amdgcn_global_load_lds(
            (const __attribute__((address_space(1))) unsigned int*)
                (hb_in + (long)(by * 32 + j) * 1024 + lane * 16),
            (__attribute__((address_space(3))) unsigned int*)(Als + (long)j * 1024),
            16, 0, 0);
    }
    // ---- Stage MX patch (gather-DMA, r17-proven).
    {
        const char* MXb = (const char*)MXc;
        #pragma unroll
        for (int jj = 0; jj < 3; ++jj) {
            const int k = w + 4 * jj;              // 0..11
            const int gt = k >> 2, rblk = k & 3;
            const long src = (long)(by * 32 + rblk * 8 + (lane >> 3)) * 6144
                           + gt * 2048 + bx * 128 + (lane & 7) * 16;
            __builtin_amdgcn_global_load_lds(
                (const __attribute__((address_space(1))) unsigned int*)(MXb + src),
                (__attribute__((address_space(3))) unsigned int*)
                    (MXls + gt * 4096 + rblk * 1024),
                16, 0, 0);
        }
    }

    // hold (f32 carry) + rbias: scalar loads in flight under the DMA drain.
    float hold[4];
    #pragma unroll
    for (int q = 0; q < 4; ++q)
        hold[q] = hf_in[(long)(m0 + hi * 4 + q) * UU + u];
    const float rbz = rbias[u];
    const float rbg = rbias[u + UU];
    const float rbh = rbias[u + 2 * UU];

    __syncthreads();   // drains all DMAs (vmcnt(0) before s_barrier)

    f32x4 acc[3] = {{0.f,0.f,0.f,0.f},{0.f,0.f,0.f,0.f},{0.f,0.f,0.f,0.f}};
    #pragma unroll
    for (int kk = 0; kk < 16; ++kk) {
        const short8 a = *(const short8*)(Als + (wy * 16 + lr) * 1024
            + ((kk * 64 + hi * 16) ^ ((lr & 7) << 4)));
        #pragma unroll
        for (int gt = 0; gt < 3; ++gt) {
            const short8 b = *(const short8*)(Bls
                + (long)(gt * 32 + wx * 16 + lr) * 1024
                + ((kk * 64 + hi * 16) ^ ((lr & 7) << 4)));
            acc[gt] = __builtin_amdgcn_mfma_f32_16x16x32_bf16(a, b, acc[gt], 0, 0, 0);
        }
    }

    #pragma unroll
    for (int q = 0; q < 4; ++q) {
        const int rloc = wy * 16 + hi * 4 + q;     // 0..31
        const float xz = *(const float*)(MXls + 0 * 4096 + rloc * 128 + (wx * 16 + lr) * 4);
        const float xr = *(const float*)(MXls + 1 * 4096 + rloc * 128 + (wx * 16 + lr) * 4);
        const float xh = *(const float*)(MXls + 2 * 4096 + rloc * 128 + (wx * 16 + lr) * 4);
        const float z = sigmoidf_(xz + acc[0][q] + rbz);
        const float r = sigmoidf_(xr + acc[1][q] + rbg);
        const float cand = xh + r * (acc[2][q] + rbh);   // reset_after
        const float hh = fmaxf(cand, 0.0f);              // relu
        const float hn = z * hold[q] + (1.0f - z) * hh;
        const int m = m0 + hi * 4 + q;
        if (!last) {
            union { __hip_bfloat16 bf; unsigned short s; } cv;
            cv.bf = __float2bfloat16(hn);
            *(unsigned short*)(hb_out + (long)m * 1024
                + ((u * 2) ^ ((m & 7) << 4))) = cv.s;
            hf_out[(long)m * UU + u] = hn;
        } else {
            out[(long)m * UU + u] = hn;
        }
    }
}

extern "C" void kernel_launch(void* const* d_in, const int* in_sizes, int n_in,
                              void* d_out, int out_size, void* d_ws, size_t ws_size,
                              hipStream_t stream)
{
    const float* x     = (const float*)d_in[0];   // [256,192,512]
    const float* ker   = (const float*)d_in[1];   // [512,1536]
    const float* rker  = (const float*)d_in[2];   // [512,1536]
    const float* ibias = (const float*)d_in[3];   // [1536]
    const float* rbias = (const float*)d_in[4];   // [1536]
    float* out = (float*)d_out;                   // [256,512]

    char* ws = (char*)d_ws;
    float*          MX   = (float*)ws;                            // 12,582,912 B
    __hip_bfloat16* Xb   = (__hip_bfloat16*)(ws + 12582912);      //  2,097,152 B
    __hip_bfloat16* Kt   = (__hip_bfloat16*)(ws + 14680064);      //  1,572,864 B
    __hip_bfloat16* Rt   = (__hip_bfloat16*)(ws + 16252928);      //  1,572,864 B
    char*           hb0  = (char*)(ws + 17825792);                //    262,144 B
    char*           hb1  = (char*)(ws + 18087936);                //    262,144 B
    // hf carry buffers reuse Xb's space (dead after gemm_mx):
    float*          hf0  = (float*)(ws + 12582912);               //    524,288 B
    float*          hf1  = (float*)(ws + 13107200);               //    524,288 B

    // Node 1: fused prologue (2 transposes + x gather/convert)
    prologue<<<2048, 256, 0, stream>>>(ker, rker, x, Kt, Rt, Xb);

    // Node 2: MX = Xsel @ kernel + input_bias (m97-style staged, 128^2 tile)
    gemm_mx<<<dim3(N3 / 128, 2048 / 128), 256, 0, stream>>>(Xb, Kt, ibias, MX);

    // Node 3: step 0 (h0 == 0 -> elementwise); writes hf1/hb1.
    gru_step0<<<512, 256, 0, stream>>>(MX, rbias, hf1, hb1);

    // Nodes 4-10: steps 1..7, kernel-per-step, DMA-staged bodies.
    for (int c = 1; c < 8; ++c) {
        const char*  hb_in = (c & 1) ? hb1 : hb0;
        const float* hf_in = (c & 1) ? hf1 : hf0;
        char*  hb_o = (c & 1) ? hb0 : hb1;
        float* hf_o = (c & 1) ? hf0 : hf1;
        gru_step<<<128, 256, 0, stream>>>(
            Rt, rbias, MX + (long)c * BB * N3, hb_in, hf_in,
            hb_o, hf_o, out, (c == 7) ? 1 : 0);
    }
}

// Round 21
// 58.010 us; speedup vs baseline: 1.8905x; 1.0251x over previous
//
#include <hip/hip_runtime.h>
#include <hip/hip_bf16.h>
#include <math.h>

// SkipGRU on MI355X, round 21: retile gemm_mx for the small shape.
// r20 confirmed: kernel-per-step + DMA body = 59.5us; per-step all-in cost
// ~4.8us (launch+flush ~3us is the floor per sequential dependency; cheaper
// than every in-kernel barrier we measured). Remaining fat: gemm_mx at 128^2
// tiles = 192 WGs (1/CU, no TLP, ~300TF at this shape per m102 curve).
// Single change: 64x128 tile, grid (12,32)=384 WGs (1.5/CU -> cross-WG TLP
// hides the 2-barrier K-loop), per-wave 32x64 out. Steps/prologue FROZEN.
//
// Only chain j=23 contributes to outputs[:, -1, :] (t=191 = chunk 7 lane 23):
// 8 sequential GRU steps over x[:, c*24+23, :], h[256,512].
//
// mfma_f32_16x16x32_bf16 layouts (learn_hip m89-verified, r4-r20 validated):
//   A: lane l holds A[l&15][(l>>4)*8 + j]
//   B: lane l holds B[(l>>4)*8 + j][l&15]  (B^T row-major -> contiguous load)
//   D: lane l reg q -> row (l>>4)*4+q, col l&15
//
// Swizzle rule (h and B): global row of 1024B stores byte o at o^((row&7)<<4);
// global_load_lds copies rows linearly; ds_read applies the same XOR
// (involution) -> conflict-free LDS reads (guide §6 G4 + m173; r13/r17-proven).

typedef float f32x4 __attribute__((ext_vector_type(4)));
typedef short short8 __attribute__((ext_vector_type(8)));

#define BB 256
#define UU 512
#define KK 512
#define N3 1536

__device__ __forceinline__ float sigmoidf_(float s) {
    return 1.0f / (1.0f + __expf(-s));
}

// Fused prologue: blocks [0,768) transpose ker, [768,1536) transpose rker,
// [1536,2048) gather+convert x.
__global__ __launch_bounds__(256)
void prologue(const float* __restrict__ ker, const float* __restrict__ rker,
              const float* __restrict__ x,
              __hip_bfloat16* __restrict__ Kt, __hip_bfloat16* __restrict__ Rtb,
              __hip_bfloat16* __restrict__ Xb)
{
    __shared__ float tile[32][33];
    const int blk = blockIdx.x;
    const int tid = threadIdx.x;
    if (blk < 1536) {
        const float* W = (blk < 768) ? ker : rker;
        __hip_bfloat16* Wt = (blk < 768) ? Kt : Rtb;
        const int b = (blk < 768) ? blk : blk - 768;
        const int xx = tid & 31, yy = tid >> 5;           // (32, 8)
        const int c0 = (b % 48) * 32;                     // C = 1536
        const int r0 = (b / 48) * 32;                     // R = 512
        #pragma unroll
        for (int i = 0; i < 32; i += 8)
            tile[yy + i][xx] = W[(long)(r0 + yy + i) * N3 + c0 + xx];
        __syncthreads();
        #pragma unroll
        for (int i = 0; i < 32; i += 8)
            Wt[(long)(c0 + yy + i) * KK + r0 + xx] = __float2bfloat16(tile[xx][yy + i]);
    } else {
        const int idx = (blk - 1536) * 256 + tid;         // one thread per 8 elems
        const int e = idx * 8;
        const int m = e >> 9;              // 0..2047 = c*256+b
        const int kk = e & 511;
        const int bb = m & 255, c = m >> 8;
        const float* src = x + (long)bb * (192 * 512) + (long)(c * 24 + 23) * 512 + kk;
        float4 v0 = *(const float4*)src;
        float4 v1 = *(const float4*)(src + 4);
        __hip_bfloat16* dst = Xb + (long)m * 512 + kk;
        dst[0] = __float2bfloat16(v0.x);
        dst[1] = __float2bfloat16(v0.y);
        dst[2] = __float2bfloat16(v0.z);
        dst[3] = __float2bfloat16(v0.w);
        dst[4] = __float2bfloat16(v1.x);
        dst[5] = __float2bfloat16(v1.y);
        dst[6] = __float2bfloat16(v1.z);
        dst[7] = __float2bfloat16(v1.w);
    }
}

// MX = A @ Bt^T + bias. 64x128 tile (BM x BN), BK=32, grid (12,32)=384 WGs.
// 4 waves as 2x2 over (64,128): wave tile 32x64 = 2x4 frags. Staged via
// global_load_lds width=16 (r16-proven recipe, smaller tile).
__global__ __launch_bounds__(256)
void gemm_mx(const __hip_bfloat16* __restrict__ A,
             const __hip_bfloat16* __restrict__ Bt,
             const float* __restrict__ bias,
             float* __restrict__ C)
{
    __shared__ char Als[4096];   // [64 rows][64B]  (32 k x 2B)
    __shared__ char Bls[8192];   // [128 cols][64B]
    const int tid = threadIdx.x;
    const int lane = tid & 63;
    const int w = tid >> 6;                 // wave 0..3
    const int wm = w >> 1, wn = w & 1;
    const int m0 = blockIdx.y * 64;
    const int n0 = blockIdx.x * 128;
    const int lr = lane & 15;
    const int hi = lane >> 4;               // 0..3

    // Staging decomposition: 64 lanes cover 16 rows x 4 16B-chunks = 1KB.
    const int srow = lane >> 2;             // 0..15
    const int scol = (lane & 3) * 16;       // byte in 64B row

    const char* Ab = (const char*)A;
    const char* Bb = (const char*)Bt;

    f32x4 acc[2][4];
    #pragma unroll
    for (int i = 0; i < 2; ++i)
        #pragma unroll
        for (int j = 0; j < 4; ++j) acc[i][j] = {0.f, 0.f, 0.f, 0.f};

    for (int ks = 0; ks < 16; ++ks) {
        const long k0b = (long)ks * 64;     // 32 k-elems * 2B
        __syncthreads();                    // prior compute done -> overwrite ok
        // A: wave w stages rows w*16..+16 (1 issue)
        __builtin_amdgcn_global_load_lds(
            (const __attribute__((address_space(1))) unsigned int*)
                (Ab + (long)(m0 + w * 16 + srow) * 1024 + k0b + scol),
            (__attribute__((address_space(3))) unsigned int*)(Als + w * 1024),
            16, 0, 0);
        // B: wave w stages rows w*32..+32 (2 issues)
        #pragma unroll
        for (int j = 0; j < 2; ++j)
            __builtin_amdgcn_global_load_lds(
                (const __attribute__((address_space(1))) unsigned int*)
                    (Bb + (long)(n0 + w * 32 + j * 16 + srow) * 1024 + k0b + scol),
                (__attribute__((address_space(3))) unsigned int*)
                    (Bls + (w * 2 + j) * 1024),
                16, 0, 0);
        __syncthreads();                    // staging complete (vmcnt drained)

        short8 a[2], b[4];
        #pragma unroll
        for (int i = 0; i < 2; ++i)
            a[i] = *(const short8*)(Als + (wm * 32 + i * 16 + lr) * 64 + hi * 16);
        #pragma unroll
        for (int j = 0; j < 4; ++j)
            b[j] = *(const short8*)(Bls + (wn * 64 + j * 16 + lr) * 64 + hi * 16);
        #pragma unroll
        for (int i = 0; i < 2; ++i)
            #pragma unroll
            for (int j = 0; j < 4; ++j)
                acc[i][j] = __builtin_amdgcn_mfma_f32_16x16x32_bf16(
                    a[i], b[j], acc[i][j], 0, 0, 0);
    }

    #pragma unroll
    for (int i = 0; i < 2; ++i)
        #pragma unroll
        for (int j = 0; j < 4; ++j) {
            const int u = n0 + wn * 64 + j * 16 + lr;
            const float bi = bias[u];
            #pragma unroll
            for (int q = 0; q < 4; ++q)
                C[(long)(m0 + wm * 32 + i * 16 + hi * 4 + q) * N3 + u]
                    = acc[i][j][q] + bi;
        }
}

// Step 0 (h==0): mi = rbias, pure elementwise. Writes f32 hf + swizzled bf16.
__global__ __launch_bounds__(256)
void gru_step0(const float* __restrict__ MX0,         // [256][1536] f32
               const float* __restrict__ rbias,       // [1536]
               float* __restrict__ hf_out,            // [256][512] f32
               char* __restrict__ hb_out)             // [256 rows][1024B] swz
{
    const int idx = blockIdx.x * 256 + threadIdx.x;   // b*512 + u
    const int b = idx >> 9;
    const int u = idx & 511;
    const float* mx = MX0 + (long)b * N3;
    const float z = sigmoidf_(mx[u]          + rbias[u]);
    const float r = sigmoidf_(mx[u + UU]     + rbias[u + UU]);
    const float cand = mx[u + 2 * UU] + r * rbias[u + 2 * UU];
    const float hh = fmaxf(cand, 0.0f);
    const float hn = (1.0f - z) * hh;
    hf_out[idx] = hn;
    union { __hip_bfloat16 bf; unsigned short s; } cv;
    cv.bf = __float2bfloat16(hn);
    *(unsigned short*)(hb_out + (long)b * 1024 + ((u * 2) ^ ((b & 7) << 4))) = cv.s;
}

// One GRU step, DMA-staged body (r17/r20-proven). 128 WGs x 256 thr.
// WG (by=blockIdx&7, bx=blockIdx>>3): rows by*32..+32, cols bx*32..+32.
__global__ __launch_bounds__(256)
void gru_step(const __hip_bfloat16* __restrict__ Rt,   // [1536][512] bf16
              const float* __restrict__ rbias,         // [1536]
              const float* __restrict__ MXc,           // [256][1536] f32 chunk c
              const char* __restrict__ hb_in,          // [256 rows][1024B] swz
              const float* __restrict__ hf_in,         // [256][512] f32
              char* __restrict__ hb_out,
              float* __restrict__ hf_out,
              float* __restrict__ out,                 // [256][512] f32
              int last)
{
    __shared__ char Bls[96 * 1024];     // B slice, source-swizzled
    __shared__ char Als[32 * 1024];     // h rows (32 x 1KB), source-swizzled
    __shared__ char MXls[12288];        // [gate][32 rows][32 cols] f32
    const int tid = threadIdx.x;
    const int lane = tid & 63;
    const int w = tid >> 6;             // wave 0..3
    const int wy = w >> 1, wx = w & 1;
    const int by = blockIdx.x & 7;
    const int bx = blockIdx.x >> 3;
    const int lr = lane & 15;
    const int hi = lane >> 4;           // 0..3
    const int m0 = by * 32 + wy * 16;
    const int n0 = bx * 32;
    const int u  = n0 + wx * 16 + lr;

    // ---- Stage B-slice (96 rows x 1024B, r13-proven).
    {
        const char* RtB = (const char*)Rt;
        #pragma unroll
        for (int i = 0; i < 24; ++i) {
            const int j  = i * 4 + w;
            const int gt = j >> 5, cc = j & 31;
            const long srcoff = (long)(gt * 512 + n0 + cc) * 1024
                              + ((lane * 16) ^ ((j & 7) << 4));
            __builtin_amdgcn_global_load_lds(
                (const __attribute__((address_space(1))) unsigned int*)(RtB + srcoff),
                (__attribute__((address_space(3))) unsigned int*)(Bls + (long)j * 1024),
                16, 0, 0);
        }
    }
    // ---- Stage A (h rows, 32 x 1KB).
    #pragma unroll
    for (int i = 0; i < 8; ++i) {
        const int j = i * 4 + w;
        __builtin_amdgcn_global_load_lds(
            (const __attribute__((address_space(1))) unsigned int*)
                (hb_in + (long)(by * 32 + j) * 1024 + lane * 16),
            (__attribute__((address_space(3))) unsigned int*)(Als + (long)j * 1024),
            16, 0, 0);
    }
    // ---- Stage MX patch (gather-DMA, r17-proven).
    {
        const char* MXb = (const char*)MXc;
        #pragma unroll
        for (int jj = 0; jj < 3; ++jj) {
            const int k = w + 4 * jj;              // 0..11
            const int gt = k >> 2, rblk = k & 3;
            const long src = (long)(by * 32 + rblk * 8 + (lane >> 3)) * 6144
                           + gt * 2048 + bx * 128 + (lane & 7) * 16;
            __builtin_amdgcn_global_load_lds(
                (const __attribute__((address_space(1))) unsigned int*)(MXb + src),
                (__attribute__((address_space(3))) unsigned int*)
                    (MXls + gt * 4096 + rblk * 1024),
                16, 0, 0);
        }
    }

    // hold (f32 carry) + rbias: scalar loads in flight under the DMA drain.
    float hold[4];
    #pragma unroll
    for (int q = 0; q < 4; ++q)
        hold[q] = hf_in[(long)(m0 + hi * 4 + q) * UU + u];
    const float rbz = rbias[u];
    const float rbg = rbias[u + UU];
    const float rbh = rbias[u + 2 * UU];

    __syncthreads();   // drains all DMAs (vmcnt(0) before s_barrier)

    f32x4 acc[3] = {{0.f,0.f,0.f,0.f},{0.f,0.f,0.f,0.f},{0.f,0.f,0.f,0.f}};
    #pragma unroll
    for (int kk = 0; kk < 16; ++kk) {
        const short8 a = *(const short8*)(Als + (wy * 16 + lr) * 1024
            + ((kk * 64 + hi * 16) ^ ((lr & 7) << 4)));
        #pragma unroll
        for (int gt = 0; gt < 3; ++gt) {
            const short8 b = *(const short8*)(Bls
                + (long)(gt * 32 + wx * 16 + lr) * 1024
                + ((kk * 64 + hi * 16) ^ ((lr & 7) << 4)));
            acc[gt] = __builtin_amdgcn_mfma_f32_16x16x32_bf16(a, b, acc[gt], 0, 0, 0);
        }
    }

    #pragma unroll
    for (int q = 0; q < 4; ++q) {
        const int rloc = wy * 16 + hi * 4 + q;     // 0..31
        const float xz = *(const float*)(MXls + 0 * 4096 + rloc * 128 + (wx * 16 + lr) * 4);
        const float xr = *(const float*)(MXls + 1 * 4096 + rloc * 128 + (wx * 16 + lr) * 4);
        const float xh = *(const float*)(MXls + 2 * 4096 + rloc * 128 + (wx * 16 + lr) * 4);
        const float z = sigmoidf_(xz + acc[0][q] + rbz);
        const float r = sigmoidf_(xr + acc[1][q] + rbg);
        const float cand = xh + r * (acc[2][q] + rbh);   // reset_after
        const float hh = fmaxf(cand, 0.0f);              // relu
        const float hn = z * hold[q] + (1.0f - z) * hh;
        const int m = m0 + hi * 4 + q;
        if (!last) {
            union { __hip_bfloat16 bf; unsigned short s; } cv;
            cv.bf = __float2bfloat16(hn);
            *(unsigned short*)(hb_out + (long)m * 1024
                + ((u * 2) ^ ((m & 7) << 4))) = cv.s;
            hf_out[(long)m * UU + u] = hn;
        } else {
            out[(long)m * UU + u] = hn;
        }
    }
}

extern "C" void kernel_launch(void* const* d_in, const int* in_sizes, int n_in,
                              void* d_out, int out_size, void* d_ws, size_t ws_size,
                              hipStream_t stream)
{
    const float* x     = (const float*)d_in[0];   // [256,192,512]
    const float* ker   = (const float*)d_in[1];   // [512,1536]
    const float* rker  = (const float*)d_in[2];   // [512,1536]
    const float* ibias = (const float*)d_in[3];   // [1536]
    const float* rbias = (const float*)d_in[4];   // [1536]
    float* out = (float*)d_out;                   // [256,512]

    char* ws = (char*)d_ws;
    float*          MX   = (float*)ws;                            // 12,582,912 B
    __hip_bfloat16* Xb   = (__hip_bfloat16*)(ws + 12582912);      //  2,097,152 B
    __hip_bfloat16* Kt   = (__hip_bfloat16*)(ws + 14680064);      //  1,572,864 B
    __hip_bfloat16* Rt   = (__hip_bfloat16*)(ws + 16252928);      //  1,572,864 B
    char*           hb0  = (char*)(ws + 17825792);                //    262,144 B
    char*           hb1  = (char*)(ws + 18087936);                //    262,144 B
    // hf carry buffers reuse Xb's space (dead after gemm_mx):
    float*          hf0  = (float*)(ws + 12582912);               //    524,288 B
    float*          hf1  = (float*)(ws + 13107200);               //    524,288 B

    // Node 1: fused prologue (2 transposes + x gather/convert)
    prologue<<<2048, 256, 0, stream>>>(ker, rker, x, Kt, Rt, Xb);

    // Node 2: MX = Xsel @ kernel + input_bias (64x128 tile, 384 WGs)
    gemm_mx<<<dim3(N3 / 128, 2048 / 64), 256, 0, stream>>>(Xb, Kt, ibias, MX);

    // Node 3: step 0 (h0 == 0 -> elementwise); writes hf1/hb1.
    gru_step0<<<512, 256, 0, stream>>>(MX, rbias, hf1, hb1);

    // Nodes 4-10: steps 1..7, kernel-per-step, DMA-staged bodies.
    for (int c = 1; c < 8; ++c) {
        const char*  hb_in = (c & 1) ? hb1 : hb0;
        const float* hf_in = (c & 1) ? hf1 : hf0;
        char*  hb_o = (c & 1) ? hb0 : hb1;
        float* hf_o = (c & 1) ? hf0 : hf1;
        gru_step<<<128, 256, 0, stream>>>(
            Rt, rbias, MX + (long)c * BB * N3, hb_in, hf_in,
            hb_o, hf_o, out, (c == 7) ? 1 : 0);
    }
}